// Round 6
// baseline (211.373 us; speedup 1.0000x reference)
//
#include <hip/hip_runtime.h>
#include <math.h>

#define N_NODES 20000
#define E_EDGES 320000
#define E_TOT   (E_EDGES + N_NODES)   // 340000 (edges + self loops)
#define NEG_SLOPE 0.2f

// prep_hist_k block ranges
#define XCAST_BLKS 2500               // 20000*128/4 elems / 256
#define W1T_BLKS   256                // 512*128 elems / 256
#define HIST_BLKS  1329               // ceil(E_TOT/256)

typedef __attribute__((ext_vector_type(8))) short bf16x8;
typedef __attribute__((ext_vector_type(4))) float f32x4;

__device__ __forceinline__ float lrelu(float x) { return x > 0.f ? x : NEG_SLOPE * x; }
__device__ __forceinline__ float bflo(unsigned int v) { return __builtin_bit_cast(float, v << 16); }
__device__ __forceinline__ float bfhi(unsigned int v) { return __builtin_bit_cast(float, v & 0xffff0000u); }
__device__ __forceinline__ unsigned int f2bf(float f) {
    return (__builtin_bit_cast(unsigned int, f) + 0x8000u) >> 16;
}

// ---- fused prep: x->bf16 cast | W1^T bf16 build | degree histogram ----------
// Harness delivers ALL integer inputs as int32 — edge_index is const int*.

__global__ void prep_hist_k(const float* __restrict__ x, unsigned int* __restrict__ xb2,
                            const float* __restrict__ W1, unsigned short* __restrict__ w1t,
                            const int* __restrict__ ei, int* __restrict__ counts) {
    int b = blockIdx.x, t = threadIdx.x;
    if (b < XCAST_BLKS) {
        int idx = b * 256 + t;                   // one float4 -> uint2 (4 bf16)
        float4 v = ((const float4*)x)[idx];
        xb2[idx * 2]     = f2bf(v.x) | (f2bf(v.y) << 16);
        xb2[idx * 2 + 1] = f2bf(v.z) | (f2bf(v.w) << 16);
    } else if (b < XCAST_BLKS + W1T_BLKS) {
        int id = (b - XCAST_BLKS) * 256 + t;     // w1t[n][k] = bf16(W1[k][n])
        int n = id >> 7, k = id & 127;
        w1t[n * 128 + k] = (unsigned short)f2bf(W1[k * 512 + n]);
    } else {
        int e = (b - XCAST_BLKS - W1T_BLKS) * 256 + t;
        if (e < E_TOT) {
            int d = (e < E_EDGES) ? ei[E_EDGES + e] : (e - E_EDGES);
            atomicAdd(&counts[d], 1);
        }
    }
}

// ---------------- single-kernel scan (1024 thr, 20 elems/thread) -------------

__global__ __launch_bounds__(1024) void scan1_k(const int* __restrict__ counts,
                                                int* __restrict__ offs,
                                                int* __restrict__ cursor) {
    __shared__ int sums[1024];
    int t = threadIdx.x;
    int base = t * 20;
    int c[20];
    int lsum = 0;
    #pragma unroll
    for (int j = 0; j < 20; j++) {
        int idx = base + j;
        c[j] = (idx < N_NODES) ? counts[idx] : 0;
        lsum += c[j];
    }
    sums[t] = lsum;
    __syncthreads();
    for (int o = 1; o < 1024; o <<= 1) {
        int u = (t >= o) ? sums[t - o] : 0;
        __syncthreads();
        sums[t] += u;
        __syncthreads();
    }
    int running = sums[t] - lsum;   // exclusive prefix
    #pragma unroll
    for (int j = 0; j < 20; j++) {
        int idx = base + j;
        if (idx < N_NODES) { offs[idx] = running; cursor[idx] = running; }
        running += c[j];
    }
    if (t == 0) offs[N_NODES] = E_TOT;
}

__global__ void scatter_k(const int* __restrict__ ei, int* __restrict__ cursor,
                          int* __restrict__ esorted) {
    int e = blockIdx.x * blockDim.x + threadIdx.x;
    if (e >= E_TOT) return;
    int s, d;
    if (e < E_EDGES) { s = ei[e]; d = ei[E_EDGES + e]; }
    else             { s = e - E_EDGES; d = s; }
    int pos = atomicAdd(&cursor[d], 1);
    esorted[pos] = s;
}

// ---- GEMM1 (bf16 MFMA, LDS-free) + fused att1 -------------------------------
// h = x@W1 via 16x16x32 MFMA. 2000 waves: wave W -> head = W&7, strip = W>>3
// (250 strips x 80 rows = 20000 exactly). The head's full B tile (64x128)
// lives in registers (16 bf16x8 frags = 64 VGPR), loaded once per wave;
// A-frags stream straight from global (16B/lane, 16 rows x 32B per issue).
// No LDS, no barriers. C/D layout: col=lane&15, row=quad*4+reg.

__global__ __launch_bounds__(256) void gemm1_k(const unsigned short* __restrict__ xb,
                                               const unsigned short* __restrict__ w1t,
                                               const float* __restrict__ att_s,
                                               const float* __restrict__ att_d,
                                               unsigned short* __restrict__ Hb,
                                               float* __restrict__ as_,
                                               float* __restrict__ ad_) {
    int t = threadIdx.x;
    int W = blockIdx.x * 4 + (t >> 6);
    int lane = t & 63;
    int head = W & 7, strip = W >> 3;           // strip < 250 always (grid=500)
    int r = lane & 15, q = lane >> 4;

    // B fragments: Bf[k0/32][nt] = B[k=k0+q*8 .. +7][n=head*64+nt*16+r]
    bf16x8 Bf[4][4];
    #pragma unroll
    for (int k = 0; k < 4; k++)
        #pragma unroll
        for (int nt = 0; nt < 4; nt++)
            Bf[k][nt] = *(const bf16x8*)&w1t[(head * 64 + nt * 16 + r) * 128 + k * 32 + q * 8];

    float sa[4], da[4];
    #pragma unroll
    for (int nt = 0; nt < 4; nt++) {
        sa[nt] = att_s[head * 64 + nt * 16 + r];
        da[nt] = att_d[head * 64 + nt * 16 + r];
    }

    for (int it = 0; it < 5; it++) {
        int m0 = strip * 80 + it * 16;
        // A frags: Af[k] = A[m=m0+r][k=k*32+q*8 .. +7]
        bf16x8 Af[4];
        #pragma unroll
        for (int k = 0; k < 4; k++)
            Af[k] = *(const bf16x8*)&xb[(m0 + r) * 128 + k * 32 + q * 8];
        f32x4 acc[4] = {{0.f,0.f,0.f,0.f},{0.f,0.f,0.f,0.f},{0.f,0.f,0.f,0.f},{0.f,0.f,0.f,0.f}};
        #pragma unroll
        for (int k = 0; k < 4; k++)
            #pragma unroll
            for (int nt = 0; nt < 4; nt++)
                acc[nt] = __builtin_amdgcn_mfma_f32_16x16x32_bf16(Af[k], Bf[k][nt], acc[nt], 0, 0, 0);
        // epilogue
        #pragma unroll
        for (int i = 0; i < 4; i++) {
            int m = m0 + q * 4 + i;
            float ps = acc[0][i]*sa[0] + acc[1][i]*sa[1] + acc[2][i]*sa[2] + acc[3][i]*sa[3];
            float pd = acc[0][i]*da[0] + acc[1][i]*da[1] + acc[2][i]*da[2] + acc[3][i]*da[3];
            ps += __shfl_xor(ps, 1); ps += __shfl_xor(ps, 2);
            ps += __shfl_xor(ps, 4); ps += __shfl_xor(ps, 8);
            pd += __shfl_xor(pd, 1); pd += __shfl_xor(pd, 2);
            pd += __shfl_xor(pd, 4); pd += __shfl_xor(pd, 8);
            if (r == 0) { as_[m * 8 + head] = ps; ad_[m * 8 + head] = pd; }
            #pragma unroll
            for (int nt = 0; nt < 4; nt++) {
                float v = acc[nt][i];
                float vn = __shfl_xor(v, 1);           // neighbor col
                if ((r & 1) == 0) {
                    unsigned int pk = f2bf(v) | (f2bf(vn) << 16);
                    *(unsigned int*)&Hb[(size_t)m * 512 + head * 64 + nt * 16 + r] = pk;
                }
            }
        }
    }
}

// ---- layer-1 softmax-aggregation: ONE WAVE PER NODE, 4 edges in flight ------
// Lane owns 8 contiguous feature elems (one uint4 bf16 per edge, coalesced
// 1 KB/row per wave). Each lane's running dsum IS the full denominator for
// its head (no reduction, no LDS). Epilogue fuses bias+ELU+512x2 projection.

__global__ __launch_bounds__(256) void agg1_k(const uint4* __restrict__ hu4,
                                              const float* __restrict__ as_,
                                              const float* __restrict__ ad_,
                                              const int* __restrict__ offs,
                                              const int* __restrict__ esorted,
                                              const float* __restrict__ b1,
                                              const float* __restrict__ W2,
                                              const float* __restrict__ as2,
                                              const float* __restrict__ ad2,
                                              float4* __restrict__ p2,
                                              float* __restrict__ a2d) {
    int i = (blockIdx.x << 2) + (threadIdx.x >> 6);
    if (i >= N_NODES) return;
    int lane = threadIdx.x & 63;
    int hd = lane >> 3;
    int off = offs[i], deg = offs[i + 1] - off;
    float adh = ad_[i * 8 + hd];
    float acc[8] = {0.f, 0.f, 0.f, 0.f, 0.f, 0.f, 0.f, 0.f};
    float dsum = 0.f;
    int e = 0;
    for (; e + 4 <= deg; e += 4) {          // 4 gathers in flight
        int ss[4]; float aa[4]; uint4 vv[4]; float cc[4];
        #pragma unroll
        for (int j = 0; j < 4; j++) ss[j] = esorted[off + e + j];
        #pragma unroll
        for (int j = 0; j < 4; j++) aa[j] = as_[ss[j] * 8 + hd];
        #pragma unroll
        for (int j = 0; j < 4; j++) vv[j] = hu4[ss[j] * 64 + lane];
        #pragma unroll
        for (int j = 0; j < 4; j++) { cc[j] = __expf(lrelu(aa[j] + adh)); dsum += cc[j]; }
        #pragma unroll
        for (int j = 0; j < 4; j++) {
            float c = cc[j]; uint4 v = vv[j];
            acc[0] += c * bflo(v.x); acc[1] += c * bfhi(v.x);
            acc[2] += c * bflo(v.y); acc[3] += c * bfhi(v.y);
            acc[4] += c * bflo(v.z); acc[5] += c * bfhi(v.z);
            acc[6] += c * bflo(v.w); acc[7] += c * bfhi(v.w);
        }
    }
    for (; e < deg; e++) {
        int s0 = esorted[off + e];
        float a0 = as_[s0 * 8 + hd];
        uint4 v0 = hu4[s0 * 64 + lane];
        float c0 = __expf(lrelu(a0 + adh));
        dsum += c0;
        acc[0] += c0 * bflo(v0.x); acc[1] += c0 * bfhi(v0.x);
        acc[2] += c0 * bflo(v0.y); acc[3] += c0 * bfhi(v0.y);
        acc[4] += c0 * bflo(v0.z); acc[5] += c0 * bfhi(v0.z);
        acc[6] += c0 * bflo(v0.w); acc[7] += c0 * bfhi(v0.w);
    }
    float inv = 1.f / dsum;          // dsum identical across the head's 8 lanes
    float4 bA = *(const float4*)&b1[lane * 8];
    float4 bB = *(const float4*)&b1[lane * 8 + 4];
    float bb[8] = {bA.x, bA.y, bA.z, bA.w, bB.x, bB.y, bB.z, bB.w};
    float p0 = 0.f, p1 = 0.f;
    #pragma unroll
    for (int j = 0; j < 8; j++) {
        float v = acc[j] * inv + bb[j];
        v = v > 0.f ? v : expm1f(v);
        int col = lane * 8 + j;
        p0 += v * W2[col * 2];
        p1 += v * W2[col * 2 + 1];
    }
    #pragma unroll
    for (int m = 1; m < 64; m <<= 1) { p0 += __shfl_xor(p0, m); p1 += __shfl_xor(p1, m); }
    if (lane == 0) {
        float a2sv = p0 * as2[0] + p1 * as2[1];
        p2[i] = make_float4(p0, p1, a2sv, 0.f);
        a2d[i] = p0 * ad2[0] + p1 * ad2[1];
    }
}

// ---- layer-2 single-pass softmax + aggregation, wave per dst node ----
// p2[s] = (h2c0, h2c1, a2s, -) : one dwordx4 gather per edge.

__global__ void agg2_k(const float4* __restrict__ p2, const float* __restrict__ a2d,
                       const int* __restrict__ offs, const int* __restrict__ esorted,
                       const float* __restrict__ b2, float* __restrict__ out) {
    int gid = blockIdx.x * blockDim.x + threadIdx.x;
    int wid = gid >> 6;
    int lane = threadIdx.x & 63;
    if (wid >= N_NODES) return;
    int off = offs[wid], deg = offs[wid + 1] - off;
    float adi = a2d[wid];
    float lsum = 0.f, o0 = 0.f, o1 = 0.f;
    for (int e = lane; e < deg; e += 64) {
        int s = esorted[off + e];
        float4 q = p2[s];
        float ex = __expf(lrelu(q.z + adi));
        lsum += ex;
        o0 += ex * q.x;
        o1 += ex * q.y;
    }
    #pragma unroll
    for (int m = 1; m < 64; m <<= 1) {
        lsum += __shfl_xor(lsum, m);
        o0 += __shfl_xor(o0, m);
        o1 += __shfl_xor(o1, m);
    }
    if (lane == 0) {
        float inv = 1.f / lsum;
        out[wid * 2]     = o0 * inv + b2[0];
        out[wid * 2 + 1] = o1 * inv + b2[1];
    }
}

// ---------------- launch ----------------

extern "C" void kernel_launch(void* const* d_in, const int* in_sizes, int n_in,
                              void* d_out, int out_size, void* d_ws, size_t ws_size,
                              hipStream_t stream) {
    const float* x        = (const float*)d_in[0];
    const int*   ei       = (const int*)d_in[1];    // int32 per harness contract
    const float* W1       = (const float*)d_in[2];
    const float* att_src1 = (const float*)d_in[3];
    const float* att_dst1 = (const float*)d_in[4];
    const float* b1       = (const float*)d_in[5];
    const float* W2       = (const float*)d_in[6];
    const float* att_src2 = (const float*)d_in[7];
    const float* att_dst2 = (const float*)d_in[8];
    const float* b2       = (const float*)d_in[9];
    float* out = (float*)d_out;

    // workspace layout (~31 MB)
    unsigned short* h1b = (unsigned short*)d_ws;         // 20000*512 bf16
    unsigned short* xb  = h1b + (size_t)N_NODES * 512;   // 20000*128 bf16
    unsigned short* w1t = xb + (size_t)N_NODES * 128;    // 512*128 bf16
    float* as1 = (float*)(w1t + 512 * 128);              // 20000*8
    float* ad1 = as1 + N_NODES * 8;                      // 20000*8
    float4* p2 = (float4*)(ad1 + N_NODES * 8);           // 20000 float4
    float* a2d = (float*)(p2 + N_NODES);                 // 20000
    int* counts  = (int*)(a2d + N_NODES);                // 20000
    int* offs    = counts + N_NODES;                     // 20001 (+pad)
    int* cursor  = offs + N_NODES + 8;                   // 20000
    int* esorted = cursor + N_NODES;                     // 340000

    hipMemsetAsync(counts, 0, N_NODES * sizeof(int), stream);

    prep_hist_k<<<XCAST_BLKS + W1T_BLKS + HIST_BLKS, 256, 0, stream>>>(
        x, (unsigned int*)xb, W1, w1t, ei, counts);
    scan1_k<<<1, 1024, 0, stream>>>(counts, offs, cursor);
    int eb = (E_TOT + 255) / 256;
    scatter_k<<<eb, 256, 0, stream>>>(ei, cursor, esorted);

    gemm1_k<<<500, 256, 0, stream>>>(xb, w1t, att_src1, att_dst1, h1b, as1, ad1);

    agg1_k<<<(N_NODES + 3) / 4, 256, 0, stream>>>((const uint4*)h1b, as1, ad1, offs,
                                                  esorted, b1, W2, att_src2, att_dst2,
                                                  p2, a2d);
    int nwb = (N_NODES * 64 + 255) / 256;
    agg2_k<<<nwb, 256, 0, stream>>>(p2, a2d, offs, esorted, b2, out);
}

// Round 7
// 192.559 us; speedup vs baseline: 1.0977x; 1.0977x over previous
//
#include <hip/hip_runtime.h>
#include <math.h>

#define N_NODES 20000
#define E_EDGES 320000
#define E_TOT   (E_EDGES + N_NODES)   // 340000 (edges + self loops)
#define NEG_SLOPE 0.2f
#define NBLK 79                       // ceil(N_NODES/256)

// prep_hist_k block ranges
#define XCAST_BLKS 2500               // 20000*128/4 elems / 256
#define W1T_BLKS   256                // 512*128 elems / 256
#define HIST_BLKS  1329               // ceil(E_TOT/256)

typedef __attribute__((ext_vector_type(8))) short bf16x8;
typedef __attribute__((ext_vector_type(4))) float f32x4;

__device__ __forceinline__ float lrelu(float x) { return x > 0.f ? x : NEG_SLOPE * x; }
__device__ __forceinline__ float bflo(unsigned int v) { return __builtin_bit_cast(float, v << 16); }
__device__ __forceinline__ float bfhi(unsigned int v) { return __builtin_bit_cast(float, v & 0xffff0000u); }
__device__ __forceinline__ unsigned int f2bf(float f) {
    return (__builtin_bit_cast(unsigned int, f) + 0x8000u) >> 16;
}

// ---- fused prep: x->bf16 cast | W1^T bf16 build | degree histogram ----------
// Harness delivers ALL integer inputs as int32 — edge_index is const int*.

__global__ void prep_hist_k(const float* __restrict__ x, unsigned int* __restrict__ xb2,
                            const float* __restrict__ W1, unsigned short* __restrict__ w1t,
                            const int* __restrict__ ei, int* __restrict__ counts) {
    int b = blockIdx.x, t = threadIdx.x;
    if (b < XCAST_BLKS) {
        int idx = b * 256 + t;                   // one float4 -> uint2 (4 bf16)
        float4 v = ((const float4*)x)[idx];
        xb2[idx * 2]     = f2bf(v.x) | (f2bf(v.y) << 16);
        xb2[idx * 2 + 1] = f2bf(v.z) | (f2bf(v.w) << 16);
    } else if (b < XCAST_BLKS + W1T_BLKS) {
        int id = (b - XCAST_BLKS) * 256 + t;     // w1t[n][k] = bf16(W1[k][n])
        int n = id >> 7, k = id & 127;
        w1t[n * 128 + k] = (unsigned short)f2bf(W1[k * 512 + n]);
    } else {
        int e = (b - XCAST_BLKS - W1T_BLKS) * 256 + t;
        if (e < E_TOT) {
            int d = (e < E_EDGES) ? ei[E_EDGES + e] : (e - E_EDGES);
            atomicAdd(&counts[d], 1);
        }
    }
}

// ---------------- hierarchical scan (coalesced, 3 small kernels) -------------

__global__ void scanA_k(const int* __restrict__ counts, int* __restrict__ local,
                        int* __restrict__ partials) {
    __shared__ int sdata[256];
    int b = blockIdx.x, t = threadIdx.x;
    int idx = b * 256 + t;
    int v = (idx < N_NODES) ? counts[idx] : 0;
    sdata[t] = v;
    __syncthreads();
    for (int o = 1; o < 256; o <<= 1) {
        int u = (t >= o) ? sdata[t - o] : 0;
        __syncthreads();
        sdata[t] += u;
        __syncthreads();
    }
    if (idx < N_NODES) local[idx] = sdata[t] - v;   // exclusive within block
    if (t == 255) partials[b] = sdata[255];
}

__global__ void scanB_k(const int* __restrict__ partials, int* __restrict__ pbase) {
    __shared__ int s[128];
    int t = threadIdx.x;
    int v = (t < NBLK) ? partials[t] : 0;
    s[t] = v;
    __syncthreads();
    for (int o = 1; o < 128; o <<= 1) {
        int u = (t >= o) ? s[t - o] : 0;
        __syncthreads();
        s[t] += u;
        __syncthreads();
    }
    if (t < NBLK) pbase[t] = s[t] - v;              // exclusive
}

__global__ void scanC_k(const int* __restrict__ local, const int* __restrict__ pbase,
                        int* __restrict__ offs, int* __restrict__ cursor) {
    int idx = blockIdx.x * 256 + threadIdx.x;
    if (idx < N_NODES) {
        int o = local[idx] + pbase[blockIdx.x];
        offs[idx] = o;
        cursor[idx] = o;
    }
    if (idx == 0) offs[N_NODES] = E_TOT;
}

__global__ void scatter_k(const int* __restrict__ ei, int* __restrict__ cursor,
                          int* __restrict__ esorted) {
    int e = blockIdx.x * blockDim.x + threadIdx.x;
    if (e >= E_TOT) return;
    int s, d;
    if (e < E_EDGES) { s = ei[e]; d = ei[E_EDGES + e]; }
    else             { s = e - E_EDGES; d = s; }
    int pos = atomicAdd(&cursor[d], 1);
    esorted[pos] = s;
}

// ---- GEMM1 (bf16 MFMA, LDS version — round-5 known-good) + fused att1 -------
// h = x@W1, 16x16x32 bf16 MFMA. Block = 64 rows x 64 cols (one head).
// LDS tiles stored [row][k] with k contiguous, +8 bf16 row pad (stride 136).
// C/D layout: col=lane&15, row=quad*4+reg.

__global__ __launch_bounds__(256) void gemm1_k(const unsigned short* __restrict__ xb,
                                               const unsigned short* __restrict__ w1t,
                                               const float* __restrict__ att_s,
                                               const float* __restrict__ att_d,
                                               unsigned short* __restrict__ Hb,
                                               float* __restrict__ as_,
                                               float* __restrict__ ad_) {
    __shared__ unsigned short As[64 * 136];
    __shared__ unsigned short Bs[64 * 136];
    int t = threadIdx.x;
    int m0 = blockIdx.x * 64;
    int head = blockIdx.y;
    #pragma unroll
    for (int c = 0; c < 4; c++) {
        int idx = c * 256 + t;
        int row = idx >> 4, c16 = idx & 15;
        uint4 v = make_uint4(0u, 0u, 0u, 0u);
        int gm = m0 + row;
        if (gm < N_NODES) v = ((const uint4*)xb)[gm * 16 + c16];
        *(uint4*)&As[row * 136 + c16 * 8] = v;
    }
    #pragma unroll
    for (int c = 0; c < 4; c++) {
        int idx = c * 256 + t;
        int row = idx >> 4, c16 = idx & 15;
        uint4 v = ((const uint4*)w1t)[(head * 64 + row) * 16 + c16];
        *(uint4*)&Bs[row * 136 + c16 * 8] = v;
    }
    __syncthreads();

    int lane = t & 63, w = t >> 6;
    int r = lane & 15, q = lane >> 4;
    f32x4 acc[4] = {{0.f,0.f,0.f,0.f},{0.f,0.f,0.f,0.f},{0.f,0.f,0.f,0.f},{0.f,0.f,0.f,0.f}};
    #pragma unroll
    for (int k0 = 0; k0 < 128; k0 += 32) {
        bf16x8 af = *(const bf16x8*)&As[(w * 16 + r) * 136 + k0 + q * 8];
        #pragma unroll
        for (int nt = 0; nt < 4; nt++) {
            bf16x8 bf = *(const bf16x8*)&Bs[(nt * 16 + r) * 136 + k0 + q * 8];
            acc[nt] = __builtin_amdgcn_mfma_f32_16x16x32_bf16(af, bf, acc[nt], 0, 0, 0);
        }
    }
    float sa[4], da[4];
    #pragma unroll
    for (int nt = 0; nt < 4; nt++) {
        sa[nt] = att_s[head * 64 + nt * 16 + r];
        da[nt] = att_d[head * 64 + nt * 16 + r];
    }
    #pragma unroll
    for (int i = 0; i < 4; i++) {
        int m = m0 + w * 16 + q * 4 + i;
        float ps = acc[0][i]*sa[0] + acc[1][i]*sa[1] + acc[2][i]*sa[2] + acc[3][i]*sa[3];
        float pd = acc[0][i]*da[0] + acc[1][i]*da[1] + acc[2][i]*da[2] + acc[3][i]*da[3];
        ps += __shfl_xor(ps, 1); ps += __shfl_xor(ps, 2);
        ps += __shfl_xor(ps, 4); ps += __shfl_xor(ps, 8);
        pd += __shfl_xor(pd, 1); pd += __shfl_xor(pd, 2);
        pd += __shfl_xor(pd, 4); pd += __shfl_xor(pd, 8);
        if (m < N_NODES) {
            if (r == 0) { as_[m * 8 + head] = ps; ad_[m * 8 + head] = pd; }
            #pragma unroll
            for (int nt = 0; nt < 4; nt++) {
                float v = acc[nt][i];
                float vn = __shfl_xor(v, 1);           // neighbor col
                if ((r & 1) == 0) {
                    unsigned int pk = f2bf(v) | (f2bf(vn) << 16);
                    *(unsigned int*)&Hb[(size_t)m * 512 + head * 64 + nt * 16 + r] = pk;
                }
            }
        }
    }
}

// ---- layer-1 softmax-aggregation: wave/node, coalesced idx + shfl broadcast --
// Phase A: one coalesced load stages 64 edge srcs into lanes. Per 8-edge
// batch: lane (j*8+h) computes coef(edge j, head h) — ONE coalesced-ish as_
// gather per 8 edges. Feature phase gets src/coef via shfl (no memory round
// trip) and issues 4 hu4 row-gathers back-to-back. Denominator: 3 shfl_xor
// at the end. No LDS. Epilogue fuses bias+ELU+512x2 layer-2 projection.

__global__ __launch_bounds__(256) void agg1_k(const uint4* __restrict__ hu4,
                                              const float* __restrict__ as_,
                                              const float* __restrict__ ad_,
                                              const int* __restrict__ offs,
                                              const int* __restrict__ esorted,
                                              const float* __restrict__ b1,
                                              const float* __restrict__ W2,
                                              const float* __restrict__ as2,
                                              const float* __restrict__ ad2,
                                              float4* __restrict__ p2,
                                              float* __restrict__ a2d) {
    int i = (blockIdx.x << 2) + (threadIdx.x >> 6);
    if (i >= N_NODES) return;
    int lane = threadIdx.x & 63;
    int hdc = lane & 7;        // coef-phase head
    int jc  = lane >> 3;       // coef-phase edge slot (0..7)
    int hdf = lane >> 3;       // feature-phase head (elems lane*8..lane*8+7)
    int off = offs[i], deg = offs[i + 1] - off;
    float adh = ad_[i * 8 + hdc];
    float acc[8] = {0.f, 0.f, 0.f, 0.f, 0.f, 0.f, 0.f, 0.f};
    float dsum = 0.f;

    for (int ebase = 0; ebase < deg; ebase += 64) {
        int nb = min(deg - ebase, 64);
        int sidx = (lane < nb) ? esorted[off + ebase + lane] : 0;
        for (int b = 0; b < nb; b += 8) {
            // coef phase: edge b+jc, head hdc
            int ej = b + jc;
            int s = __shfl(sidx, ej);                  // 0 if lane ej inactive
            float av = as_[s * 8 + hdc];
            float cf = (ej < nb) ? __expf(lrelu(av + adh)) : 0.f;
            dsum += cf;
            // feature phase: 4 edges in flight per sub-batch (uniform guard)
            #pragma unroll
            for (int jj = 0; jj < 8; jj += 4) {
                if (b + jj < nb) {
                    int s0 = __shfl(sidx, b + jj);
                    int s1 = __shfl(sidx, b + jj + 1);
                    int s2 = __shfl(sidx, b + jj + 2);
                    int s3 = __shfl(sidx, b + jj + 3);
                    float c0 = __shfl(cf, (jj + 0) * 8 + hdf);
                    float c1 = __shfl(cf, (jj + 1) * 8 + hdf);
                    float c2 = __shfl(cf, (jj + 2) * 8 + hdf);
                    float c3 = __shfl(cf, (jj + 3) * 8 + hdf);
                    uint4 v0 = hu4[s0 * 64 + lane];
                    uint4 v1 = hu4[s1 * 64 + lane];
                    uint4 v2 = hu4[s2 * 64 + lane];
                    uint4 v3 = hu4[s3 * 64 + lane];
                    acc[0] += c0 * bflo(v0.x); acc[1] += c0 * bfhi(v0.x);
                    acc[2] += c0 * bflo(v0.y); acc[3] += c0 * bfhi(v0.y);
                    acc[4] += c0 * bflo(v0.z); acc[5] += c0 * bfhi(v0.z);
                    acc[6] += c0 * bflo(v0.w); acc[7] += c0 * bfhi(v0.w);
                    acc[0] += c1 * bflo(v1.x); acc[1] += c1 * bfhi(v1.x);
                    acc[2] += c1 * bflo(v1.y); acc[3] += c1 * bfhi(v1.y);
                    acc[4] += c1 * bflo(v1.z); acc[5] += c1 * bfhi(v1.z);
                    acc[6] += c1 * bflo(v1.w); acc[7] += c1 * bfhi(v1.w);
                    acc[0] += c2 * bflo(v2.x); acc[1] += c2 * bfhi(v2.x);
                    acc[2] += c2 * bflo(v2.y); acc[3] += c2 * bfhi(v2.y);
                    acc[4] += c2 * bflo(v2.z); acc[5] += c2 * bfhi(v2.z);
                    acc[6] += c2 * bflo(v2.w); acc[7] += c2 * bfhi(v2.w);
                    acc[0] += c3 * bflo(v3.x); acc[1] += c3 * bfhi(v3.x);
                    acc[2] += c3 * bflo(v3.y); acc[3] += c3 * bfhi(v3.y);
                    acc[4] += c3 * bflo(v3.z); acc[5] += c3 * bfhi(v3.z);
                    acc[6] += c3 * bflo(v3.w); acc[7] += c3 * bfhi(v3.w);
                }
            }
        }
    }
    // full denominator: sum coef partials over the 8 j-slots (bits 3..5)
    dsum += __shfl_xor(dsum, 8);
    dsum += __shfl_xor(dsum, 16);
    dsum += __shfl_xor(dsum, 32);
    // lane l now holds denom for head l&7; fetch denom for feature head hdf
    float inv = 1.f / __shfl(dsum, hdf);
    float4 bA = *(const float4*)&b1[lane * 8];
    float4 bB = *(const float4*)&b1[lane * 8 + 4];
    float bb[8] = {bA.x, bA.y, bA.z, bA.w, bB.x, bB.y, bB.z, bB.w};
    float p0 = 0.f, p1 = 0.f;
    #pragma unroll
    for (int j = 0; j < 8; j++) {
        float v = acc[j] * inv + bb[j];
        v = v > 0.f ? v : expm1f(v);
        int col = lane * 8 + j;
        p0 += v * W2[col * 2];
        p1 += v * W2[col * 2 + 1];
    }
    #pragma unroll
    for (int m = 1; m < 64; m <<= 1) { p0 += __shfl_xor(p0, m); p1 += __shfl_xor(p1, m); }
    if (lane == 0) {
        float a2sv = p0 * as2[0] + p1 * as2[1];
        p2[i] = make_float4(p0, p1, a2sv, 0.f);
        a2d[i] = p0 * ad2[0] + p1 * ad2[1];
    }
}

// ---- layer-2 single-pass softmax + aggregation, wave per dst node ----
// p2[s] = (h2c0, h2c1, a2s, -) : one dwordx4 gather per edge.

__global__ void agg2_k(const float4* __restrict__ p2, const float* __restrict__ a2d,
                       const int* __restrict__ offs, const int* __restrict__ esorted,
                       const float* __restrict__ b2, float* __restrict__ out) {
    int gid = blockIdx.x * blockDim.x + threadIdx.x;
    int wid = gid >> 6;
    int lane = threadIdx.x & 63;
    if (wid >= N_NODES) return;
    int off = offs[wid], deg = offs[wid + 1] - off;
    float adi = a2d[wid];
    float lsum = 0.f, o0 = 0.f, o1 = 0.f;
    for (int e = lane; e < deg; e += 64) {
        int s = esorted[off + e];
        float4 q = p2[s];
        float ex = __expf(lrelu(q.z + adi));
        lsum += ex;
        o0 += ex * q.x;
        o1 += ex * q.y;
    }
    #pragma unroll
    for (int m = 1; m < 64; m <<= 1) {
        lsum += __shfl_xor(lsum, m);
        o0 += __shfl_xor(o0, m);
        o1 += __shfl_xor(o1, m);
    }
    if (lane == 0) {
        float inv = 1.f / lsum;
        out[wid * 2]     = o0 * inv + b2[0];
        out[wid * 2 + 1] = o1 * inv + b2[1];
    }
}

// ---------------- launch ----------------

extern "C" void kernel_launch(void* const* d_in, const int* in_sizes, int n_in,
                              void* d_out, int out_size, void* d_ws, size_t ws_size,
                              hipStream_t stream) {
    const float* x        = (const float*)d_in[0];
    const int*   ei       = (const int*)d_in[1];    // int32 per harness contract
    const float* W1       = (const float*)d_in[2];
    const float* att_src1 = (const float*)d_in[3];
    const float* att_dst1 = (const float*)d_in[4];
    const float* b1       = (const float*)d_in[5];
    const float* W2       = (const float*)d_in[6];
    const float* att_src2 = (const float*)d_in[7];
    const float* att_dst2 = (const float*)d_in[8];
    const float* b2       = (const float*)d_in[9];
    float* out = (float*)d_out;

    // workspace layout (~31 MB)
    unsigned short* h1b = (unsigned short*)d_ws;         // 20000*512 bf16
    unsigned short* xb  = h1b + (size_t)N_NODES * 512;   // 20000*128 bf16
    unsigned short* w1t = xb + (size_t)N_NODES * 128;    // 512*128 bf16
    float* as1 = (float*)(w1t + 512 * 128);              // 20000*8
    float* ad1 = as1 + N_NODES * 8;                      // 20000*8
    float4* p2 = (float4*)(ad1 + N_NODES * 8);           // 20000 float4
    float* a2d = (float*)(p2 + N_NODES);                 // 20000
    int* counts  = (int*)(a2d + N_NODES);                // 20000
    int* offs    = counts + N_NODES;                     // 20001 (+pad)
    int* cursor  = offs + N_NODES + 8;                   // 20000
    int* local   = cursor + N_NODES;                     // 20000
    int* partials= local + N_NODES;                      // 80
    int* pbase   = partials + 128;                       // 80
    int* esorted = pbase + 128;                          // 340000

    hipMemsetAsync(counts, 0, N_NODES * sizeof(int), stream);

    prep_hist_k<<<XCAST_BLKS + W1T_BLKS + HIST_BLKS, 256, 0, stream>>>(
        x, (unsigned int*)xb, W1, w1t, ei, counts);
    scanA_k<<<NBLK, 256, 0, stream>>>(counts, local, partials);
    scanB_k<<<1, 128, 0, stream>>>(partials, pbase);
    scanC_k<<<NBLK, 256, 0, stream>>>(local, pbase, offs, cursor);
    int eb = (E_TOT + 255) / 256;
    scatter_k<<<eb, 256, 0, stream>>>(ei, cursor, esorted);

    dim3 ggrid((N_NODES + 63) / 64, 8);
    gemm1_k<<<ggrid, 256, 0, stream>>>(xb, w1t, att_src1, att_dst1, h1b, as1, ad1);

    agg1_k<<<(N_NODES + 3) / 4, 256, 0, stream>>>((const uint4*)h1b, as1, ad1, offs,
                                                  esorted, b1, W2, att_src2, att_dst2,
                                                  p2, a2d);
    int nwb = (N_NODES * 64 + 255) / 256;
    agg2_k<<<nwb, 256, 0, stream>>>(p2, a2d, offs, esorted, b2, out);
}